// Round 5
// baseline (328.395 us; speedup 1.0000x reference)
//
#include <hip/hip_runtime.h>
#include <hip/hip_bf16.h>

// SelfAttention_592705487560 — N=4096, D=128, H=8
// scores = V·Q^T (flash roles: query=v, key=q, value=k), softmax over q-index.
// Round 5: 4-wave/256-thr kattn blocks (32 v-rows/wave, 128/block), z-split x4;
// plds removed — P redistribution fully in-register (cvt_pk_bf16 + shfl_xor
// exchange); LOG2E folded into V; klds chunk-XOR swizzle (8-way -> 4-way);
// kwt x4 parallelism; koutm 512 blocks with 4-way merge fused.
// ws bytes: WTh/WTl 786432 ea | WoT 262144 | Qh/Vh/Vl/Kt 8388608 ea |
//           Opart 33554432 | ml 1048576  => ~70 MB

typedef __attribute__((ext_vector_type(8))) short short8;   // 8 x bf16 (4 VGPRs)
typedef __attribute__((ext_vector_type(4))) float f32x4;

#define MFMA(a,b,c) __builtin_amdgcn_mfma_f32_16x16x32_bf16((a),(b),(c),0,0,0)
#define LOG2E 1.44269504088896340736f
#define DEFER_THR 11.5442f   // 8 nats in log2 units

#define AS1 __attribute__((address_space(1)))
#define AS3 __attribute__((address_space(3)))
static __device__ __forceinline__ void gld16(const void* g, void* l) {
  __builtin_amdgcn_global_load_lds((const AS1 void*)g, (AS3 void*)l, 16, 0, 0);
}

static __device__ __forceinline__ unsigned short f2bf(float f) {
  union { float f; unsigned u; } v; v.f = f;
  unsigned r = v.u + 0x7fffu + ((v.u >> 16) & 1u);   // round-to-nearest-even
  return (unsigned short)(r >> 16);
}
static __device__ __forceinline__ float bf2f(unsigned short h) {
  union { unsigned u; float f; } v; v.u = ((unsigned)h) << 16; return v.f;
}
static __device__ __forceinline__ void split2(float f, unsigned short& hi, unsigned short& lo) {
  hi = f2bf(f);
  lo = f2bf(f - bf2f(hi));
}
// packed f32x2 -> bf16x2 (RNE), lo in low 16 bits
static __device__ __forceinline__ unsigned cvt_pk_bf16(float lo, float hi) {
  unsigned r;
  asm("v_cvt_pk_bf16_f32 %0, %1, %2" : "=v"(r) : "v"(lo), "v"(hi));
  return r;
}

// ---- in-register P -> PV B-fragment exchange ----
// Input: p[0..3] = P[v][m=g*4+0..3], p[4..7] = P[v][m=16+g*4+0..3] (own lane g).
// Output t[0..3]: u32 bf16-pairs so that {t0,t1,t2,t3} is the 16x16x32 B-frag
// (lane needs k=m = g*8..g*8+7).  Derivation: pair idx p=m/2; src lane holds
// pairs {2g, 2g+1, 8+2g, 9+2g}; target wants {4g..4g+3}.  Verified per-lane.
static __device__ __forceinline__ void pexch(const float* p, int lane, unsigned* t) {
  unsigned A = cvt_pk_bf16(p[0], p[1]);
  unsigned B = cvt_pk_bf16(p[2], p[3]);
  unsigned C = cvt_pk_bf16(p[4], p[5]);
  unsigned D = cvt_pk_bf16(p[6], p[7]);
  bool lo32 = (lane & 32) == 0;
  unsigned A32 = __shfl_xor(A, 32), B32 = __shfl_xor(B, 32);
  unsigned C32 = __shfl_xor(C, 32), D32 = __shfl_xor(D, 32);
  unsigned u0 = lo32 ? A : C32;    // [A.g0, A.g1, C.g0, C.g1]
  unsigned u1 = lo32 ? A32 : C;    // [A.g2, A.g3, C.g2, C.g3]
  unsigned v0 = lo32 ? B : D32;
  unsigned v1 = lo32 ? B32 : D;
  bool eg = (lane & 16) == 0;
  unsigned su1 = __shfl_xor(u1, 16), su0 = __shfl_xor(u0, 16);
  unsigned sv1 = __shfl_xor(v1, 16), sv0 = __shfl_xor(v0, 16);
  t[0] = eg ? u0 : su1;            // [A.g0, A.g2, C.g0, C.g2]
  t[1] = eg ? v0 : sv1;
  t[2] = eg ? su0 : u1;            // [A.g1, A.g3, C.g1, C.g3]
  t[3] = eg ? sv0 : v1;
}

// ---------------- prep: transpose weights to bf16 hi/lo (128 blocks) --------
// mat 0..7 Wq, 8..15 Wk, 16..23 Wv -> WTh/WTl[mat][e][d]; mat 24..31 -> WoT.
__global__ __launch_bounds__(256) void kwt(const float* __restrict__ Wq,
                                           const float* __restrict__ Wk,
                                           const float* __restrict__ Wv,
                                           const float* __restrict__ Wo,
                                           unsigned short* __restrict__ WTh,
                                           unsigned short* __restrict__ WTl,
                                           unsigned short* __restrict__ WoT) {
  __shared__ float lds[32 * 130];
  int b = blockIdx.x, t = threadIdx.x;
  int mat = b >> 2, q = b & 3;
  const float* src = (mat < 8)  ? Wq + mat * 16384
                   : (mat < 16) ? Wk + (mat - 8) * 16384
                   : (mat < 24) ? Wv + (mat - 16) * 16384
                                : Wo + (mat - 24) * 16384;
  src += q * 32 * 128;
#pragma unroll
  for (int i = 0; i < 4; ++i) {              // stage 32 rows x 128 cols f32
    int lin = i * 1024 + t * 4;
    int row = lin >> 7, col = lin & 127;
    float4 v = *reinterpret_cast<const float4*>(src + lin);
    lds[row * 130 + col + 0] = v.x;
    lds[row * 130 + col + 1] = v.y;
    lds[row * 130 + col + 2] = v.z;
    lds[row * 130 + col + 3] = v.w;
  }
  __syncthreads();
  int e = t >> 1, ks = (t & 1) * 16;
  float buf[16];
#pragma unroll
  for (int j = 0; j < 16; ++j) buf[j] = lds[(ks + j) * 130 + e];
  int kg = q * 32 + ks;
  if (mat < 24) {
    unsigned short* dh = WTh + mat * 16384 + e * 128 + kg;
    unsigned short* dl = WTl + mat * 16384 + e * 128 + kg;
#pragma unroll
    for (int c = 0; c < 2; ++c) {
      short8 oh, ol;
#pragma unroll
      for (int jj = 0; jj < 8; ++jj) {
        unsigned short h, l; split2(buf[c * 8 + jj], h, l);
        oh[jj] = (short)h; ol[jj] = (short)l;
      }
      *reinterpret_cast<short8*>(dh + c * 8) = oh;
      *reinterpret_cast<short8*>(dl + c * 8) = ol;
    }
  } else {
    unsigned short* dst = WoT + e * 1024 + (mat - 24) * 128 + kg;
#pragma unroll
    for (int c = 0; c < 2; ++c) {
      short8 o;
#pragma unroll
      for (int jj = 0; jj < 8; ++jj) o[jj] = (short)f2bf(buf[c * 8 + jj]);
      *reinterpret_cast<short8*>(dst + c * 8) = o;
    }
  }
}

// ---------------- fused projections (reads f32 x, splits inline) ----------------
// grid (64 nb, 8 h). Q (3-term, hi store), V (3-term, *LOG2E, hi/lo), K -> Kt.
__global__ __launch_bounds__(256) void kprojf(const float* __restrict__ x,
                                              const unsigned short* __restrict__ WThg,
                                              const unsigned short* __restrict__ WTlg,
                                              const float* __restrict__ bq,
                                              const float* __restrict__ bk,
                                              const float* __restrict__ bv,
                                              unsigned short* __restrict__ Qh,
                                              unsigned short* __restrict__ Vh,
                                              unsigned short* __restrict__ Vl,
                                              unsigned short* __restrict__ Kt) {
  __shared__ __align__(16) unsigned char lds[64 * 128 * 2];
  int nb = blockIdx.x, h = blockIdx.y;
  int t = threadIdx.x, lane = t & 63, w = t >> 6;
  int r = lane & 15, g = lane >> 4;
  int rowbase = nb * 64 + w * 16;

  short8 ah[4], al[4];
#pragma unroll
  for (int kc = 0; kc < 4; ++kc) {
    const float* xp = x + (size_t)(rowbase + r) * 128 + kc * 32 + g * 8;
    float4 f0 = *reinterpret_cast<const float4*>(xp);
    float4 f1 = *reinterpret_cast<const float4*>(xp + 4);
    unsigned short hi_, lo_;
    split2(f0.x, hi_, lo_); ah[kc][0] = (short)hi_; al[kc][0] = (short)lo_;
    split2(f0.y, hi_, lo_); ah[kc][1] = (short)hi_; al[kc][1] = (short)lo_;
    split2(f0.z, hi_, lo_); ah[kc][2] = (short)hi_; al[kc][2] = (short)lo_;
    split2(f0.w, hi_, lo_); ah[kc][3] = (short)hi_; al[kc][3] = (short)lo_;
    split2(f1.x, hi_, lo_); ah[kc][4] = (short)hi_; al[kc][4] = (short)lo_;
    split2(f1.y, hi_, lo_); ah[kc][5] = (short)hi_; al[kc][5] = (short)lo_;
    split2(f1.z, hi_, lo_); ah[kc][6] = (short)hi_; al[kc][6] = (short)lo_;
    split2(f1.w, hi_, lo_); ah[kc][7] = (short)hi_; al[kc][7] = (short)lo_;
  }

  f32x4 acc[8];
  // ---- Q (slot 0): 3-term, store hi only ----
  {
    const unsigned short* Wth = WThg + (0 * 8 + h) * 16384;
    const unsigned short* Wtl = WTlg + (0 * 8 + h) * 16384;
#pragma unroll
    for (int ct = 0; ct < 8; ++ct) acc[ct] = (f32x4){0.f, 0.f, 0.f, 0.f};
#pragma unroll
    for (int ct = 0; ct < 8; ++ct) {
#pragma unroll
      for (int kc = 0; kc < 4; ++kc) {
        short8 bh = *reinterpret_cast<const short8*>(Wth + (ct * 16 + r) * 128 + kc * 32 + g * 8);
        short8 bl = *reinterpret_cast<const short8*>(Wtl + (ct * 16 + r) * 128 + kc * 32 + g * 8);
        acc[ct] = MFMA(ah[kc], bh, acc[ct]);
        acc[ct] = MFMA(ah[kc], bl, acc[ct]);
        acc[ct] = MFMA(al[kc], bh, acc[ct]);
      }
    }
    unsigned short* dh = Qh + (size_t)h * 4096 * 128;
#pragma unroll
    for (int ct = 0; ct < 8; ++ct) {
      int e = ct * 16 + r;
      float bb = bq[h * 128 + e];
#pragma unroll
      for (int rr = 0; rr < 4; ++rr) {
        int n = rowbase + g * 4 + rr;
        dh[n * 128 + e] = f2bf(acc[ct][rr] + bb);
      }
    }
  }
  // ---- V (slot 2): 3-term, scale by LOG2E, store hi/lo ----
  {
    const unsigned short* Wth = WThg + (2 * 8 + h) * 16384;
    const unsigned short* Wtl = WTlg + (2 * 8 + h) * 16384;
#pragma unroll
    for (int ct = 0; ct < 8; ++ct) acc[ct] = (f32x4){0.f, 0.f, 0.f, 0.f};
#pragma unroll
    for (int ct = 0; ct < 8; ++ct) {
#pragma unroll
      for (int kc = 0; kc < 4; ++kc) {
        short8 bh = *reinterpret_cast<const short8*>(Wth + (ct * 16 + r) * 128 + kc * 32 + g * 8);
        short8 bl = *reinterpret_cast<const short8*>(Wtl + (ct * 16 + r) * 128 + kc * 32 + g * 8);
        acc[ct] = MFMA(ah[kc], bh, acc[ct]);
        acc[ct] = MFMA(ah[kc], bl, acc[ct]);
        acc[ct] = MFMA(al[kc], bh, acc[ct]);
      }
    }
    unsigned short* dh = Vh + (size_t)h * 4096 * 128;
    unsigned short* dl = Vl + (size_t)h * 4096 * 128;
#pragma unroll
    for (int ct = 0; ct < 8; ++ct) {
      int e = ct * 16 + r;
      float bb = bv[h * 128 + e];
#pragma unroll
      for (int rr = 0; rr < 4; ++rr) {
        int n = rowbase + g * 4 + rr;
        unsigned short hi_, lo_; split2((acc[ct][rr] + bb) * LOG2E, hi_, lo_);
        dh[n * 128 + e] = hi_;
        dl[n * 128 + e] = lo_;
      }
    }
  }
  // ---- K (slot 1): 1-term, transpose via LDS -> Kt[h][e][n] ----
  {
    const unsigned short* Wth = WThg + (1 * 8 + h) * 16384;
#pragma unroll
    for (int ct = 0; ct < 8; ++ct) acc[ct] = (f32x4){0.f, 0.f, 0.f, 0.f};
#pragma unroll
    for (int ct = 0; ct < 8; ++ct) {
#pragma unroll
      for (int kc = 0; kc < 4; ++kc) {
        short8 bh = *reinterpret_cast<const short8*>(Wth + (ct * 16 + r) * 128 + kc * 32 + g * 8);
        acc[ct] = MFMA(ah[kc], bh, acc[ct]);
      }
    }
#pragma unroll
    for (int ct = 0; ct < 8; ++ct) {
      int e = ct * 16 + r;
      float bb = bk[h * 128 + e];
#pragma unroll
      for (int rr = 0; rr < 4; ++rr) {
        int n = w * 16 + g * 4 + rr;
        unsigned off = ((unsigned)(n * 128 + e) * 2u) ^ ((unsigned)(n & 7) << 4);
        *reinterpret_cast<unsigned short*>(lds + off) = f2bf(acc[ct][rr] + bb);
      }
    }
    __syncthreads();
    int e = t >> 1, n0 = (t & 1) * 32;
    unsigned short buf[32];
#pragma unroll
    for (int j = 0; j < 32; ++j) {
      int n = n0 + j;
      unsigned off = ((unsigned)(n * 128 + e) * 2u) ^ ((unsigned)(n & 7) << 4);
      buf[j] = *reinterpret_cast<unsigned short*>(lds + off);
    }
    unsigned short* dst = Kt + ((size_t)h * 128 + e) * 4096 + nb * 64 + n0;
#pragma unroll
    for (int c = 0; c < 4; ++c) {
      short8 o;
#pragma unroll
      for (int jj = 0; jj < 8; ++jj) o[jj] = (short)buf[c * 8 + jj];
      *reinterpret_cast<short8*>(dst + c * 8) = o;
    }
  }
}

// ---------------- flash attention: 4 waves x 32 v-rows, z-split x4 ----------------
// grid (8 h, 32 nb, 4 z); 256 threads. LDS 32KB (no plds). In-register P exchange.
__global__ __launch_bounds__(256, 3) void kattn(
    const unsigned short* __restrict__ Qg,   // [h][n][d] bf16
    const unsigned short* __restrict__ Kt,   // [h][d][n] bf16
    const unsigned short* __restrict__ Vh,   // [h][n][d] bf16 hi (pre-scaled LOG2E)
    const unsigned short* __restrict__ Vl,   // [h][n][d] bf16 lo
    unsigned short* __restrict__ Opart,      // [z][h][n][d] bf16 (unnormalized)
    float2* __restrict__ ml) {               // [z][h][n] = {m, l}  (log2 domain)
  __shared__ __align__(16) unsigned char qlds[2][8192];   // [buf][32m][256B] swizzled
  __shared__ __align__(16) unsigned char klds[2][8192];   // [buf][128d][64B] chunk-XOR
  const int h = blockIdx.x, nb = blockIdx.y, z = blockIdx.z;
  const int t = threadIdx.x, lane = t & 63, w = t >> 6;
  const int r = lane & 15, g = lane >> 4;
  const unsigned char* Qb = (const unsigned char*)(Qg + (size_t)h * 4096 * 128);
  const unsigned char* Kb = (const unsigned char*)(Kt + (size_t)h * 128 * 4096);

  // V fragments for 32 rows (two v-blocks)
  const int vbase = nb * 128 + w * 32;
  short8 va0h[4], va0l[4], va1h[4], va1l[4];
#pragma unroll
  for (int kc = 0; kc < 4; ++kc) {
    size_t o0 = (size_t)h * 4096 * 128 + (size_t)(vbase + r) * 128 + kc * 32 + g * 8;
    size_t o1 = (size_t)h * 4096 * 128 + (size_t)(vbase + 16 + r) * 128 + kc * 32 + g * 8;
    va0h[kc] = *reinterpret_cast<const short8*>(Vh + o0);
    va0l[kc] = *reinterpret_cast<const short8*>(Vl + o0);
    va1h[kc] = *reinterpret_cast<const short8*>(Vh + o1);
    va1l[kc] = *reinterpret_cast<const short8*>(Vl + o1);
  }

  f32x4 oacc0[8], oacc1[8];
#pragma unroll
  for (int dt = 0; dt < 8; ++dt) {
    oacc0[dt] = (f32x4){0.f, 0.f, 0.f, 0.f};
    oacc1[dt] = (f32x4){0.f, 0.f, 0.f, 0.f};
  }
  float m0run = -3e38f, l0run = 0.f, m1run = -3e38f, l1run = 0.f;
  const int mt0 = z * 32;                    // 32 m-tiles of 32 per z-slice

#define STAGE(buf, mtile) do {                                                   \
    const unsigned char* qsrc = Qb + (size_t)(mtile) * 8192;                     \
    const unsigned char* ksrc = Kb + (size_t)(mtile) * 64;                       \
    _Pragma("unroll")                                                            \
    for (int j = 0; j < 2; ++j) {                                                \
      int row = j * 16 + (t >> 4);                                               \
      gld16(qsrc + (size_t)row * 256 + (((unsigned)(t & 15) * 16) ^ ((unsigned)(row & 7) << 4)), \
            &qlds[buf][j * 4096 + t * 16]);                                      \
    }                                                                            \
    _Pragma("unroll")                                                            \
    for (int j = 0; j < 2; ++j) {                                                \
      int d = j * 64 + (t >> 2);                                                 \
      int c = (t & 3) ^ (d & 3);                                                 \
      gld16(ksrc + (size_t)d * 8192 + (unsigned)c * 16,                          \
            &klds[buf][j * 4096 + t * 16]);                                      \
    }                                                                            \
  } while (0)

  STAGE(0, mt0);
  __syncthreads();

  const unsigned qsw = ((unsigned)(r & 7)) << 4;
  const unsigned kxor = ((unsigned)(g ^ (r & 3))) << 4;
  for (int it = 0; it < 32; ++it) {
    const int buf = it & 1;
    if (it < 31) STAGE(buf ^ 1, mt0 + it + 1);
    // ---- scores: 4 C-tiles [m 32][v 32], 2-term (vh + vl), log2 domain ----
    f32x4 s00 = (f32x4){0.f, 0.f, 0.f, 0.f};
    f32x4 s10 = (f32x4){0.f, 0.f, 0.f, 0.f};
    f32x4 s01 = (f32x4){0.f, 0.f, 0.f, 0.f};
    f32x4 s11 = (f32x4){0.f, 0.f, 0.f, 0.f};
    __builtin_amdgcn_s_setprio(1);
#pragma unroll
    for (int kc = 0; kc < 4; ++kc) {
      unsigned col = (unsigned)(kc * 64 + g * 16);
      short8 q0 = *reinterpret_cast<const short8*>(&qlds[buf][(unsigned)r * 256 + (col ^ qsw)]);
      short8 q1 = *reinterpret_cast<const short8*>(&qlds[buf][(unsigned)(16 + r) * 256 + (col ^ qsw)]);
      s00 = MFMA(q0, va0h[kc], s00);
      s10 = MFMA(q1, va0h[kc], s10);
      s01 = MFMA(q0, va1h[kc], s01);
      s11 = MFMA(q1, va1h[kc], s11);
      s00 = MFMA(q0, va0l[kc], s00);
      s10 = MFMA(q1, va0l[kc], s10);
      s01 = MFMA(q0, va1l[kc], s01);
      s11 = MFMA(q1, va1l[kc], s11);
    }
    __builtin_amdgcn_s_setprio(0);
    // ---- online softmax (per-lane scalar m/l; reduce over g via 2 shfl) ----
    float mx0 = fmaxf(fmaxf(fmaxf(s00[0], s00[1]), fmaxf(s00[2], s00[3])),
                      fmaxf(fmaxf(s10[0], s10[1]), fmaxf(s10[2], s10[3])));
    float mx1 = fmaxf(fmaxf(fmaxf(s01[0], s01[1]), fmaxf(s01[2], s01[3])),
                      fmaxf(fmaxf(s11[0], s11[1]), fmaxf(s11[2], s11[3])));
    mx0 = fmaxf(mx0, __shfl_xor(mx0, 16)); mx0 = fmaxf(mx0, __shfl_xor(mx0, 32));
    mx1 = fmaxf(mx1, __shfl_xor(mx1, 16)); mx1 = fmaxf(mx1, __shfl_xor(mx1, 32));
    if (__any(mx0 > m0run + DEFER_THR)) {
      float nm = fmaxf(m0run, mx0);
      float sc = exp2f(m0run - nm);
      l0run *= sc;
#pragma unroll
      for (int dt = 0; dt < 8; ++dt) oacc0[dt] *= sc;
      m0run = nm;
    }
    if (__any(mx1 > m1run + DEFER_THR)) {
      float nm = fmaxf(m1run, mx1);
      float sc = exp2f(m1run - nm);
      l1run *= sc;
#pragma unroll
      for (int dt = 0; dt < 8; ++dt) oacc1[dt] *= sc;
      m1run = nm;
    }
    float p0[8], p1[8];
#pragma unroll
    for (int j = 0; j < 4; ++j) {
      p0[j]     = exp2f(s00[j] - m0run);
      p0[4 + j] = exp2f(s10[j] - m0run);
      p1[j]     = exp2f(s01[j] - m1run);
      p1[4 + j] = exp2f(s11[j] - m1run);
    }
    float ps0 = ((p0[0] + p0[1]) + (p0[2] + p0[3])) + ((p0[4] + p0[5]) + (p0[6] + p0[7]));
    float ps1 = ((p1[0] + p1[1]) + (p1[2] + p1[3])) + ((p1[4] + p1[5]) + (p1[6] + p1[7]));
    ps0 += __shfl_xor(ps0, 16); ps0 += __shfl_xor(ps0, 32);
    ps1 += __shfl_xor(ps1, 16); ps1 += __shfl_xor(ps1, 32);
    l0run += ps0;
    l1run += ps1;
    // ---- P -> B-fragments entirely in registers ----
    union { unsigned u[4]; short8 s8; } pa0u, pa1u;
    pexch(p0, lane, pa0u.u);
    pexch(p1, lane, pa1u.u);
    // ---- PV: out^T C[d][v] += K[d][m] * P[v][m]; kb shared across v-blocks ----
    __builtin_amdgcn_s_setprio(1);
#pragma unroll
    for (int dt = 0; dt < 8; ++dt) {
      short8 kb = *reinterpret_cast<const short8*>(
          &klds[buf][((unsigned)(dt * 16 + r) * 64) + kxor]);
      oacc0[dt] = MFMA(kb, pa0u.s8, oacc0[dt]);
      oacc1[dt] = MFMA(kb, pa1u.s8, oacc1[dt]);
    }
    __builtin_amdgcn_s_setprio(0);
    __syncthreads();
  }
#undef STAGE
  // epilogue: unnormalized bf16 partials + (m,l)
  unsigned short* Ob = Opart + (size_t)(z * 8 + h) * 4096 * 128;
#pragma unroll
  for (int dt = 0; dt < 8; ++dt) {
#pragma unroll
    for (int rr = 0; rr < 4; ++rr) {
      int d = dt * 16 + g * 4 + rr;
      Ob[(size_t)(vbase + r) * 128 + d]      = f2bf(oacc0[dt][rr]);
      Ob[(size_t)(vbase + 16 + r) * 128 + d] = f2bf(oacc1[dt][rr]);
    }
  }
  if (g == 0) ml[(size_t)(z * 8 + h) * 4096 + vbase + r]      = make_float2(m0run, l0run);
  if (g == 1) ml[(size_t)(z * 8 + h) * 4096 + vbase + 16 + r] = make_float2(m1run, l1run);
}

// ---------------- fused 4-way merge + output projection ----------------
// grid (256 rb, 2 ch); wave w -> 16 cols at ch*64 + w*16.
__global__ __launch_bounds__(256) void koutm(const unsigned short* __restrict__ Opart,
                                             const float2* __restrict__ ml,
                                             const unsigned short* __restrict__ WoT,
                                             const float* __restrict__ bo,
                                             float* __restrict__ out) {
  int rb = blockIdx.x, ch = blockIdx.y;
  int t = threadIdx.x, lane = t & 63, w = t >> 6;
  int r = lane & 15, g = lane >> 4;
  int row = rb * 16 + r;                         // A row (n index)
  float a[4][8];
#pragma unroll
  for (int h = 0; h < 8; ++h) {
    float2 m0 = ml[(size_t)(0 * 8 + h) * 4096 + row];
    float2 m1 = ml[(size_t)(1 * 8 + h) * 4096 + row];
    float2 m2 = ml[(size_t)(2 * 8 + h) * 4096 + row];
    float2 m3 = ml[(size_t)(3 * 8 + h) * 4096 + row];
    float M = fmaxf(fmaxf(m0.x, m1.x), fmaxf(m2.x, m3.x));
    float e0 = exp2f(m0.x - M), e1 = exp2f(m1.x - M);
    float e2 = exp2f(m2.x - M), e3 = exp2f(m3.x - M);
    float inv = 1.0f / (m0.y * e0 + m1.y * e1 + m2.y * e2 + m3.y * e3);
    a[0][h] = e0 * inv; a[1][h] = e1 * inv; a[2][h] = e2 * inv; a[3][h] = e3 * inv;
  }
  int e0c = ch * 64 + w * 16;
  f32x4 acc = (f32x4){0.f, 0.f, 0.f, 0.f};
#pragma unroll
  for (int kc = 0; kc < 32; ++kc) {
    int h = kc >> 2;
    int dof = (kc & 3) * 32 + g * 8;
    float af[8];
#pragma unroll
    for (int j = 0; j < 8; ++j) af[j] = 0.f;
#pragma unroll
    for (int zz = 0; zz < 4; ++zz) {
      short8 o = *reinterpret_cast<const short8*>(
          Opart + ((size_t)(zz * 8 + h) * 4096 + row) * 128 + dof);
      float az = a[zz][h];
#pragma unroll
      for (int j = 0; j < 8; ++j) af[j] += bf2f((unsigned short)o[j]) * az;
    }
    union { unsigned u[4]; short8 s8; } afp;
#pragma unroll
    for (int j = 0; j < 4; ++j) afp.u[j] = cvt_pk_bf16(af[2 * j], af[2 * j + 1]);
    short8 b0 = *reinterpret_cast<const short8*>(WoT + (size_t)(e0c + r) * 1024 + kc * 32 + g * 8);
    acc = MFMA(afp.s8, b0, acc);
  }
  float bov = bo[e0c + r];
#pragma unroll
  for (int rr = 0; rr < 4; ++rr) {
    int n = rb * 16 + g * 4 + rr;
    out[(size_t)n * 128 + e0c + r] = acc[rr] + bov;
  }
}

extern "C" void kernel_launch(void* const* d_in, const int* in_sizes, int n_in,
                              void* d_out, int out_size, void* d_ws, size_t ws_size,
                              hipStream_t stream) {
  const float* x  = (const float*)d_in[0];
  const float* Wq = (const float*)d_in[1];
  const float* bq = (const float*)d_in[2];
  const float* Wk = (const float*)d_in[3];
  const float* bk = (const float*)d_in[4];
  const float* Wv = (const float*)d_in[5];
  const float* bv = (const float*)d_in[6];
  const float* Wo = (const float*)d_in[7];
  const float* bo = (const float*)d_in[8];
  float* out = (float*)d_out;

  unsigned short* ws = (unsigned short*)d_ws;    // ~70 MB
  unsigned short* WTh   = ws;                    // 393216
  unsigned short* WTl   = WTh + 393216;          // 393216
  unsigned short* WoT   = WTl + 393216;          // 131072
  unsigned short* Qh    = WoT + 131072;          // 4194304
  unsigned short* Vh    = Qh + 4194304;          // 4194304
  unsigned short* Vl    = Vh + 4194304;          // 4194304
  unsigned short* Kt    = Vl + 4194304;          // 4194304
  unsigned short* Opart = Kt + 4194304;          // 16777216
  float2*         mlp   = (float2*)(Opart + 16777216);  // 131072 float2

  kwt<<<128, 256, 0, stream>>>(Wq, Wk, Wv, Wo, WTh, WTl, WoT);
  kprojf<<<dim3(64, 8), 256, 0, stream>>>(x, WTh, WTl, bq, bk, bv, Qh, Vh, Vl, Kt);
  kattn<<<dim3(8, 32, 4), 256, 0, stream>>>(Qh, Kt, Vh, Vl, Opart, mlp);
  koutm<<<dim3(256, 2), 256, 0, stream>>>(Opart, mlp, WoT, bo, out);
}

// Round 9
// 274.723 us; speedup vs baseline: 1.1954x; 1.1954x over previous
//
#include <hip/hip_runtime.h>
#include <hip/hip_bf16.h>

// SelfAttention_592705487560 — N=4096, D=128, H=8
// scores = V·Q^T (flash roles: query=v, key=q, value=k), softmax over q-index.
// Round 9: REVERT to Round-4 passing structure (kattn/koutm byte-identical to
// R4; kwt = R5's 128-block version). Single change: projections restored to
// z-split dispatch (grid 64x8x3, one of Q/V/K per block — R3's validated
// pattern) with R4's validated in-register x hi/lo split. The m-tile-64
// kattn rewrite (R6-R8) is abandoned: 3 rounds, no root cause found.

typedef __attribute__((ext_vector_type(8))) short short8;   // 8 x bf16 (4 VGPRs)
typedef __attribute__((ext_vector_type(4))) float f32x4;

#define MFMA(a,b,c) __builtin_amdgcn_mfma_f32_16x16x32_bf16((a),(b),(c),0,0,0)
#define LOG2E 1.44269504088896340736f
#define DEFER_THR 8.0f

#define AS1 __attribute__((address_space(1)))
#define AS3 __attribute__((address_space(3)))
static __device__ __forceinline__ void gld16(const void* g, void* l) {
  __builtin_amdgcn_global_load_lds((const AS1 void*)g, (AS3 void*)l, 16, 0, 0);
}

static __device__ __forceinline__ unsigned short f2bf(float f) {
  union { float f; unsigned u; } v; v.f = f;
  unsigned r = v.u + 0x7fffu + ((v.u >> 16) & 1u);   // round-to-nearest-even
  return (unsigned short)(r >> 16);
}
static __device__ __forceinline__ float bf2f(unsigned short h) {
  union { unsigned u; float f; } v; v.u = ((unsigned)h) << 16; return v.f;
}
static __device__ __forceinline__ void split2(float f, unsigned short& hi, unsigned short& lo) {
  hi = f2bf(f);
  lo = f2bf(f - bf2f(hi));
}
static __device__ __forceinline__ unsigned cvt_pk_bf16(float lo, float hi) {
  unsigned r;
  asm("v_cvt_pk_bf16_f32 %0, %1, %2" : "=v"(r) : "v"(lo), "v"(hi));
  return r;
}

// ---------------- prep: transpose weights to bf16 hi/lo (128 blocks) --------
// mat 0..7 Wq, 8..15 Wk, 16..23 Wv -> WTh/WTl[mat][e][d]; mat 24..31 -> WoT.
__global__ __launch_bounds__(256) void kwt(const float* __restrict__ Wq,
                                           const float* __restrict__ Wk,
                                           const float* __restrict__ Wv,
                                           const float* __restrict__ Wo,
                                           unsigned short* __restrict__ WTh,
                                           unsigned short* __restrict__ WTl,
                                           unsigned short* __restrict__ WoT) {
  __shared__ float lds[32 * 130];
  int b = blockIdx.x, t = threadIdx.x;
  int mat = b >> 2, q = b & 3;
  const float* src = (mat < 8)  ? Wq + mat * 16384
                   : (mat < 16) ? Wk + (mat - 8) * 16384
                   : (mat < 24) ? Wv + (mat - 16) * 16384
                                : Wo + (mat - 24) * 16384;
  src += q * 32 * 128;
#pragma unroll
  for (int i = 0; i < 4; ++i) {              // stage 32 rows x 128 cols f32
    int lin = i * 1024 + t * 4;
    int row = lin >> 7, col = lin & 127;
    float4 v = *reinterpret_cast<const float4*>(src + lin);
    lds[row * 130 + col + 0] = v.x;
    lds[row * 130 + col + 1] = v.y;
    lds[row * 130 + col + 2] = v.z;
    lds[row * 130 + col + 3] = v.w;
  }
  __syncthreads();
  int e = t >> 1, ks = (t & 1) * 16;
  float buf[16];
#pragma unroll
  for (int j = 0; j < 16; ++j) buf[j] = lds[(ks + j) * 130 + e];
  int kg = q * 32 + ks;
  if (mat < 24) {
    unsigned short* dh = WTh + mat * 16384 + e * 128 + kg;
    unsigned short* dl = WTl + mat * 16384 + e * 128 + kg;
#pragma unroll
    for (int c = 0; c < 2; ++c) {
      short8 oh, ol;
#pragma unroll
      for (int jj = 0; jj < 8; ++jj) {
        unsigned short h, l; split2(buf[c * 8 + jj], h, l);
        oh[jj] = (short)h; ol[jj] = (short)l;
      }
      *reinterpret_cast<short8*>(dh + c * 8) = oh;
      *reinterpret_cast<short8*>(dl + c * 8) = ol;
    }
  } else {
    unsigned short* dst = WoT + e * 1024 + (mat - 24) * 128 + kg;
#pragma unroll
    for (int c = 0; c < 2; ++c) {
      short8 o;
#pragma unroll
      for (int jj = 0; jj < 8; ++jj) o[jj] = (short)f2bf(buf[c * 8 + jj]);
      *reinterpret_cast<short8*>(dst + c * 8) = o;
    }
  }
}

// ---------------- projections, z-split (R3 dispatch, R4 per-slot code) ------
// grid (64 nb, 8 h, 3 z): z=0 Q (3-term, hi), z=1 V (3-term, hi/lo), z=2 K->Kt.
__global__ __launch_bounds__(256) void kproj(const float* __restrict__ x,
                                             const unsigned short* __restrict__ WThg,
                                             const unsigned short* __restrict__ WTlg,
                                             const float* __restrict__ bq,
                                             const float* __restrict__ bk,
                                             const float* __restrict__ bv,
                                             unsigned short* __restrict__ Qh,
                                             unsigned short* __restrict__ Vh,
                                             unsigned short* __restrict__ Vl,
                                             unsigned short* __restrict__ Kt) {
  __shared__ __align__(16) unsigned char lds[64 * 128 * 2];
  int nb = blockIdx.x, h = blockIdx.y, z = blockIdx.z;
  int t = threadIdx.x, lane = t & 63, w = t >> 6;
  int r = lane & 15, g = lane >> 4;
  int rowbase = nb * 64 + w * 16;

  // x rows -> hi/lo fragments in registers (R4-validated)
  short8 ah[4], al[4];
#pragma unroll
  for (int kc = 0; kc < 4; ++kc) {
    const float* xp = x + (size_t)(rowbase + r) * 128 + kc * 32 + g * 8;
    float4 f0 = *reinterpret_cast<const float4*>(xp);
    float4 f1 = *reinterpret_cast<const float4*>(xp + 4);
    unsigned short hi_, lo_;
    split2(f0.x, hi_, lo_); ah[kc][0] = (short)hi_; al[kc][0] = (short)lo_;
    split2(f0.y, hi_, lo_); ah[kc][1] = (short)hi_; al[kc][1] = (short)lo_;
    split2(f0.z, hi_, lo_); ah[kc][2] = (short)hi_; al[kc][2] = (short)lo_;
    split2(f0.w, hi_, lo_); ah[kc][3] = (short)hi_; al[kc][3] = (short)lo_;
    split2(f1.x, hi_, lo_); ah[kc][4] = (short)hi_; al[kc][4] = (short)lo_;
    split2(f1.y, hi_, lo_); ah[kc][5] = (short)hi_; al[kc][5] = (short)lo_;
    split2(f1.z, hi_, lo_); ah[kc][6] = (short)hi_; al[kc][6] = (short)lo_;
    split2(f1.w, hi_, lo_); ah[kc][7] = (short)hi_; al[kc][7] = (short)lo_;
  }

  f32x4 acc[8];
#pragma unroll
  for (int ct = 0; ct < 8; ++ct) acc[ct] = (f32x4){0.f, 0.f, 0.f, 0.f};

  if (z == 0) {
    // ---- Q (slot 0): 3-term, store hi only ----
    const unsigned short* Wth = WThg + (0 * 8 + h) * 16384;
    const unsigned short* Wtl = WTlg + (0 * 8 + h) * 16384;
#pragma unroll
    for (int ct = 0; ct < 8; ++ct) {
#pragma unroll
      for (int kc = 0; kc < 4; ++kc) {
        short8 bh = *reinterpret_cast<const short8*>(Wth + (ct * 16 + r) * 128 + kc * 32 + g * 8);
        short8 bl = *reinterpret_cast<const short8*>(Wtl + (ct * 16 + r) * 128 + kc * 32 + g * 8);
        acc[ct] = MFMA(ah[kc], bh, acc[ct]);
        acc[ct] = MFMA(ah[kc], bl, acc[ct]);
        acc[ct] = MFMA(al[kc], bh, acc[ct]);
      }
    }
    unsigned short* dh = Qh + (size_t)h * 4096 * 128;
#pragma unroll
    for (int ct = 0; ct < 8; ++ct) {
      int e = ct * 16 + r;
      float bb = bq[h * 128 + e];
#pragma unroll
      for (int rr = 0; rr < 4; ++rr) {
        int n = rowbase + g * 4 + rr;
        dh[n * 128 + e] = f2bf(acc[ct][rr] + bb);
      }
    }
  } else if (z == 1) {
    // ---- V (slot 2): 3-term, store hi/lo (NO scaling — R4 semantics) ----
    const unsigned short* Wth = WThg + (2 * 8 + h) * 16384;
    const unsigned short* Wtl = WTlg + (2 * 8 + h) * 16384;
#pragma unroll
    for (int ct = 0; ct < 8; ++ct) {
#pragma unroll
      for (int kc = 0; kc < 4; ++kc) {
        short8 bh = *reinterpret_cast<const short8*>(Wth + (ct * 16 + r) * 128 + kc * 32 + g * 8);
        short8 bl = *reinterpret_cast<const short8*>(Wtl + (ct * 16 + r) * 128 + kc * 32 + g * 8);
        acc[ct] = MFMA(ah[kc], bh, acc[ct]);
        acc[ct] = MFMA(ah[kc], bl, acc[ct]);
        acc[ct] = MFMA(al[kc], bh, acc[ct]);
      }
    }
    unsigned short* dh = Vh + (size_t)h * 4096 * 128;
    unsigned short* dl = Vl + (size_t)h * 4096 * 128;
#pragma unroll
    for (int ct = 0; ct < 8; ++ct) {
      int e = ct * 16 + r;
      float bb = bv[h * 128 + e];
#pragma unroll
      for (int rr = 0; rr < 4; ++rr) {
        int n = rowbase + g * 4 + rr;
        unsigned short hi_, lo_; split2(acc[ct][rr] + bb, hi_, lo_);
        dh[n * 128 + e] = hi_;
        dl[n * 128 + e] = lo_;
      }
    }
  } else {
    // ---- K (slot 1): 1-term, transpose via LDS -> Kt[h][e][n] ----
    const unsigned short* Wth = WThg + (1 * 8 + h) * 16384;
#pragma unroll
    for (int ct = 0; ct < 8; ++ct) {
#pragma unroll
      for (int kc = 0; kc < 4; ++kc) {
        short8 bh = *reinterpret_cast<const short8*>(Wth + (ct * 16 + r) * 128 + kc * 32 + g * 8);
        acc[ct] = MFMA(ah[kc], bh, acc[ct]);
      }
    }
#pragma unroll
    for (int ct = 0; ct < 8; ++ct) {
      int e = ct * 16 + r;
      float bb = bk[h * 128 + e];
#pragma unroll
      for (int rr = 0; rr < 4; ++rr) {
        int n = w * 16 + g * 4 + rr;
        unsigned off = ((unsigned)(n * 128 + e) * 2u) ^ ((unsigned)(n & 7) << 4);
        *reinterpret_cast<unsigned short*>(lds + off) = f2bf(acc[ct][rr] + bb);
      }
    }
    __syncthreads();
    int e = t >> 1, n0 = (t & 1) * 32;
    unsigned short buf[32];
#pragma unroll
    for (int j = 0; j < 32; ++j) {
      int n = n0 + j;
      unsigned off = ((unsigned)(n * 128 + e) * 2u) ^ ((unsigned)(n & 7) << 4);
      buf[j] = *reinterpret_cast<unsigned short*>(lds + off);
    }
    unsigned short* dst = Kt + ((size_t)h * 128 + e) * 4096 + nb * 64 + n0;
#pragma unroll
    for (int c = 0; c < 4; ++c) {
      short8 o;
#pragma unroll
      for (int jj = 0; jj < 8; ++jj) o[jj] = (short)buf[c * 8 + jj];
      *reinterpret_cast<short8*>(dst + c * 8) = o;
    }
  }
}

// ---------------- flash attention: 2 waves x 32 v-rows, m-split x2 (R4) -----
// grid (8 h, 64 nb, 2 z); 128 threads. Unnormalized bf16 partials + (m,l).
__global__ __launch_bounds__(128, 2) void kattn(
    const unsigned short* __restrict__ Qg,   // [h][n][d] bf16
    const unsigned short* __restrict__ Kt,   // [h][d][n] bf16
    const unsigned short* __restrict__ Vh,   // [h][n][d] bf16 hi
    const unsigned short* __restrict__ Vl,   // [h][n][d] bf16 lo
    unsigned short* __restrict__ Opart,      // [z][h][n][d] bf16 (unnormalized)
    float2* __restrict__ ml) {               // [z][h][n] = {m, l}
  __shared__ __align__(16) unsigned char qlds[2][8192];     // [buf][32m][256B] swizzled
  __shared__ __align__(16) unsigned char klds[2][8192];     // [buf][128d][64B] linear
  __shared__ __align__(16) unsigned short plds[2][32 * 40]; // per-wave P[v][m], stride 40
  const int h = blockIdx.x, nb = blockIdx.y, z = blockIdx.z;
  const int t = threadIdx.x, lane = t & 63, w = t >> 6;
  const int r = lane & 15, g = lane >> 4;
  const unsigned char* Qb = (const unsigned char*)(Qg + (size_t)h * 4096 * 128);
  const unsigned char* Kb = (const unsigned char*)(Kt + (size_t)h * 128 * 4096);

  // V fragments for 32 rows (two v-blocks)
  const int vbase = nb * 64 + w * 32;
  short8 va0h[4], va0l[4], va1h[4], va1l[4];
#pragma unroll
  for (int kc = 0; kc < 4; ++kc) {
    size_t o0 = (size_t)h * 4096 * 128 + (size_t)(vbase + r) * 128 + kc * 32 + g * 8;
    size_t o1 = (size_t)h * 4096 * 128 + (size_t)(vbase + 16 + r) * 128 + kc * 32 + g * 8;
    va0h[kc] = *reinterpret_cast<const short8*>(Vh + o0);
    va0l[kc] = *reinterpret_cast<const short8*>(Vl + o0);
    va1h[kc] = *reinterpret_cast<const short8*>(Vh + o1);
    va1l[kc] = *reinterpret_cast<const short8*>(Vl + o1);
  }

  f32x4 oacc0[8], oacc1[8];
#pragma unroll
  for (int dt = 0; dt < 8; ++dt) {
    oacc0[dt] = (f32x4){0.f, 0.f, 0.f, 0.f};
    oacc1[dt] = (f32x4){0.f, 0.f, 0.f, 0.f};
  }
  float m0run = -3e38f, l0run = 0.f, m1run = -3e38f, l1run = 0.f;
  const int mt0 = z * 64;

#define STAGE(buf, mtile) do {                                                   \
    const unsigned char* qsrc = Qb + (size_t)(mtile) * 8192;                     \
    const unsigned char* ksrc = Kb + (size_t)(mtile) * 64;                       \
    _Pragma("unroll")                                                            \
    for (int j = 0; j < 4; ++j) {                                                \
      int row = j * 8 + (t >> 4);                                                \
      gld16(qsrc + (size_t)row * 256 + (((unsigned)(t & 15) * 16) ^ ((unsigned)(row & 7) << 4)), \
            &qlds[buf][j * 2048 + t * 16]);                                      \
    }                                                                            \
    _Pragma("unroll")                                                            \
    for (int j = 0; j < 4; ++j) {                                                \
      int row = j * 32 + (t >> 2);                                               \
      gld16(ksrc + (size_t)row * 8192 + (unsigned)(t & 3) * 16,                  \
            &klds[buf][j * 2048 + t * 16]);                                      \
    }                                                                            \
  } while (0)

  STAGE(0, mt0);
  __syncthreads();

  const unsigned qsw = ((unsigned)(r & 7)) << 4;
  for (int it = 0; it < 64; ++it) {
    const int buf = it & 1;
    if (it < 63) STAGE(buf ^ 1, mt0 + it + 1);
    // ---- scores: 4 C-tiles [m 32][v 32], 2-term (vh + vl) ----
    f32x4 s00 = (f32x4){0.f, 0.f, 0.f, 0.f};
    f32x4 s10 = (f32x4){0.f, 0.f, 0.f, 0.f};
    f32x4 s01 = (f32x4){0.f, 0.f, 0.f, 0.f};
    f32x4 s11 = (f32x4){0.f, 0.f, 0.f, 0.f};
    __builtin_amdgcn_s_setprio(1);
#pragma unroll
    for (int kc = 0; kc < 4; ++kc) {
      unsigned col = (unsigned)(kc * 64 + g * 16);
      short8 q0 = *reinterpret_cast<const short8*>(&qlds[buf][(unsigned)r * 256 + (col ^ qsw)]);
      short8 q1 = *reinterpret_cast<const short8*>(&qlds[buf][(unsigned)(16 + r) * 256 + (col ^ qsw)]);
      s00 = MFMA(q0, va0h[kc], s00);
      s10 = MFMA(q1, va0h[kc], s10);
      s01 = MFMA(q0, va1h[kc], s01);
      s11 = MFMA(q1, va1h[kc], s11);
      s00 = MFMA(q0, va0l[kc], s00);
      s10 = MFMA(q1, va0l[kc], s10);
      s01 = MFMA(q0, va1l[kc], s01);
      s11 = MFMA(q1, va1l[kc], s11);
    }
    __builtin_amdgcn_s_setprio(0);
    // ---- online softmax (per-lane scalar m/l; reduce over g via 2 shfl) ----
    float mx0 = fmaxf(fmaxf(fmaxf(s00[0], s00[1]), fmaxf(s00[2], s00[3])),
                      fmaxf(fmaxf(s10[0], s10[1]), fmaxf(s10[2], s10[3])));
    float mx1 = fmaxf(fmaxf(fmaxf(s01[0], s01[1]), fmaxf(s01[2], s01[3])),
                      fmaxf(fmaxf(s11[0], s11[1]), fmaxf(s11[2], s11[3])));
    mx0 = fmaxf(mx0, __shfl_xor(mx0, 16)); mx0 = fmaxf(mx0, __shfl_xor(mx0, 32));
    mx1 = fmaxf(mx1, __shfl_xor(mx1, 16)); mx1 = fmaxf(mx1, __shfl_xor(mx1, 32));
    if (__any(mx0 > m0run + DEFER_THR)) {
      float nm = fmaxf(m0run, mx0);
      float sc = exp2f((m0run - nm) * LOG2E);
      l0run *= sc;
#pragma unroll
      for (int dt = 0; dt < 8; ++dt) oacc0[dt] *= sc;
      m0run = nm;
    }
    if (__any(mx1 > m1run + DEFER_THR)) {
      float nm = fmaxf(m1run, mx1);
      float sc = exp2f((m1run - nm) * LOG2E);
      l1run *= sc;
#pragma unroll
      for (int dt = 0; dt < 8; ++dt) oacc1[dt] *= sc;
      m1run = nm;
    }
    float p0[8], p1[8];
#pragma unroll
    for (int j = 0; j < 4; ++j) {
      p0[j]     = exp2f((s00[j] - m0run) * LOG2E);
      p0[4 + j] = exp2f((s10[j] - m0run) * LOG2E);
      p1[j]     = exp2f((s01[j] - m1run) * LOG2E);
      p1[4 + j] = exp2f((s11[j] - m1run) * LOG2E);
    }
    float ps0 = ((p0[0] + p0[1]) + (p0[2] + p0[3])) + ((p0[4] + p0[5]) + (p0[6] + p0[7]));
    float ps1 = ((p1[0] + p1[1]) + (p1[2] + p1[3])) + ((p1[4] + p1[5]) + (p1[6] + p1[7]));
    ps0 += __shfl_xor(ps0, 16); ps0 += __shfl_xor(ps0, 32);
    ps1 += __shfl_xor(ps1, 16); ps1 += __shfl_xor(ps1, 32);
    l0run += ps0;
    l1run += ps1;
    // ---- P -> plds[v][m] (rows r / 16+r), packed 8B writes ----
    {
      ushort4 a, b, c, d;
      a.x = f2bf(p0[0]); a.y = f2bf(p0[1]); a.z = f2bf(p0[2]); a.w = f2bf(p0[3]);
      b.x = f2bf(p0[4]); b.y = f2bf(p0[5]); b.z = f2bf(p0[6]); b.w = f2bf(p0[7]);
      c.x = f2bf(p1[0]); c.y = f2bf(p1[1]); c.z = f2bf(p1[2]); c.w = f2bf(p1[3]);
      d.x = f2bf(p1[4]); d.y = f2bf(p1[5]); d.z = f2bf(p1[6]); d.w = f2bf(p1[7]);
      unsigned short* pw = &plds[w][0];
      *reinterpret_cast<ushort4*>(pw + r * 40 + g * 4)             = a;
      *reinterpret_cast<ushort4*>(pw + r * 40 + 16 + g * 4)        = b;
      *reinterpret_cast<ushort4*>(pw + (16 + r) * 40 + g * 4)      = c;
      *reinterpret_cast<ushort4*>(pw + (16 + r) * 40 + 16 + g * 4) = d;
    }
    short8 pa0 = *reinterpret_cast<const short8*>(&plds[w][r * 40 + g * 8]);
    short8 pa1 = *reinterpret_cast<const short8*>(&plds[w][(16 + r) * 40 + g * 8]);
    // ---- PV: out^T C[d][v] += K[d][m] * P[v][m]; kb shared across v-blocks ----
    __builtin_amdgcn_s_setprio(1);
#pragma unroll
    for (int dt = 0; dt < 8; ++dt) {
      short8 kb = *reinterpret_cast<const short8*>(&klds[buf][(unsigned)(dt * 16 + r) * 64 + (unsigned)(g * 16)]);
      oacc0[dt] = MFMA(kb, pa0, oacc0[dt]);
      oacc1[dt] = MFMA(kb, pa1, oacc1[dt]);
    }
    __builtin_amdgcn_s_setprio(0);
    __syncthreads();
  }
#undef STAGE
  // epilogue: unnormalized bf16 partials + (m,l)
  unsigned short* Ob = Opart + (size_t)(z * 8 + h) * 4096 * 128;
#pragma unroll
  for (int dt = 0; dt < 8; ++dt) {
#pragma unroll
    for (int rr = 0; rr < 4; ++rr) {
      int d = dt * 16 + g * 4 + rr;
      Ob[(size_t)(vbase + r) * 128 + d]      = f2bf(oacc0[dt][rr]);
      Ob[(size_t)(vbase + 16 + r) * 128 + d] = f2bf(oacc1[dt][rr]);
    }
  }
  if (g == 0) ml[(size_t)(z * 8 + h) * 4096 + vbase + r]      = make_float2(m0run, l0run);
  if (g == 1) ml[(size_t)(z * 8 + h) * 4096 + vbase + 16 + r] = make_float2(m1run, l1run);
}

// ---------------- fused merge + output projection (R4 exact) ----------------
__global__ __launch_bounds__(256) void koutm(const unsigned short* __restrict__ Opart,
                                             const float2* __restrict__ ml,
                                             const unsigned short* __restrict__ WoT,
                                             const float* __restrict__ bo,
                                             float* __restrict__ out) {
  int rb = blockIdx.x;
  int t = threadIdx.x, lane = t & 63, w = t >> 6;
  int r = lane & 15, g = lane >> 4;
  int row = rb * 16 + r;                         // A row (n index)
  float a0[8], a1[8];
#pragma unroll
  for (int h = 0; h < 8; ++h) {
    float2 m0 = ml[(size_t)h * 4096 + row];
    float2 m1 = ml[(size_t)(8 + h) * 4096 + row];
    float M = fmaxf(m0.x, m1.x);
    float e0 = exp2f((m0.x - M) * LOG2E);
    float e1 = exp2f((m1.x - M) * LOG2E);
    float inv = 1.0f / (m0.y * e0 + m1.y * e1);
    a0[h] = e0 * inv; a1[h] = e1 * inv;
  }
  f32x4 acc0 = (f32x4){0.f, 0.f, 0.f, 0.f};
  f32x4 acc1 = (f32x4){0.f, 0.f, 0.f, 0.f};
#pragma unroll
  for (int kc = 0; kc < 32; ++kc) {
    int h = kc >> 2;
    int dof = (kc & 3) * 32 + g * 8;
    short8 o0 = *reinterpret_cast<const short8*>(Opart + ((size_t)h * 4096 + row) * 128 + dof);
    short8 o1 = *reinterpret_cast<const short8*>(Opart + ((size_t)(8 + h) * 4096 + row) * 128 + dof);
    short8 af;
#pragma unroll
    for (int j = 0; j < 8; ++j)
      af[j] = (short)f2bf(bf2f((unsigned short)o0[j]) * a0[h] +
                          bf2f((unsigned short)o1[j]) * a1[h]);
    short8 b0 = *reinterpret_cast<const short8*>(WoT + (size_t)(w * 32 + r) * 1024 + kc * 32 + g * 8);
    short8 b1 = *reinterpret_cast<const short8*>(WoT + (size_t)(w * 32 + 16 + r) * 1024 + kc * 32 + g * 8);
    acc0 = MFMA(af, b0, acc0);
    acc1 = MFMA(af, b1, acc1);
  }
#pragma unroll
  for (int rr = 0; rr < 4; ++rr) {
    int n = rb * 16 + g * 4 + rr;
    out[(size_t)n * 128 + w * 32 + r]      = acc0[rr] + bo[w * 32 + r];
    out[(size_t)n * 128 + w * 32 + 16 + r] = acc1[rr] + bo[w * 32 + 16 + r];
  }
}

extern "C" void kernel_launch(void* const* d_in, const int* in_sizes, int n_in,
                              void* d_out, int out_size, void* d_ws, size_t ws_size,
                              hipStream_t stream) {
  const float* x  = (const float*)d_in[0];
  const float* Wq = (const float*)d_in[1];
  const float* bq = (const float*)d_in[2];
  const float* Wk = (const float*)d_in[3];
  const float* bk = (const float*)d_in[4];
  const float* Wv = (const float*)d_in[5];
  const float* bv = (const float*)d_in[6];
  const float* Wo = (const float*)d_in[7];
  const float* bo = (const float*)d_in[8];
  float* out = (float*)d_out;

  unsigned short* ws = (unsigned short*)d_ws;    // ~53 MB
  unsigned short* WTh   = ws;                    // 393216
  unsigned short* WTl   = WTh + 393216;          // 393216
  unsigned short* WoT   = WTl + 393216;          // 131072
  unsigned short* Qh    = WoT + 131072;          // 4194304
  unsigned short* Vh    = Qh + 4194304;          // 4194304
  unsigned short* Vl    = Vh + 4194304;          // 4194304
  unsigned short* Kt    = Vl + 4194304;          // 4194304
  unsigned short* Opart = Kt + 4194304;          // 8388608
  float2*         mlp   = (float2*)(Opart + 8388608);   // 65536 float2

  kwt<<<128, 256, 0, stream>>>(Wq, Wk, Wv, Wo, WTh, WTl, WoT);
  kproj<<<dim3(64, 8, 3), 256, 0, stream>>>(x, WTh, WTl, bq, bk, bv, Qh, Vh, Vl, Kt);
  kattn<<<dim3(8, 64, 2), 128, 0, stream>>>(Qh, Kt, Vh, Vl, Opart, mlp);
  koutm<<<256, 256, 0, stream>>>(Opart, mlp, WoT, bo, out);
}